// Round 13
// baseline (209.020 us; speedup 1.0000x reference)
//
#include <hip/hip_runtime.h>
#include <math.h>

#define NN   6144
#define FIN  512
#define HIDN 64
#define NC   40
#define NH   3
#define CAP  128           // max neighbors kept (deg ~61 +/- 8; 128 ~ 8.3 sigma)
#define NCHUNK (CAP / 64)
#define LALPHA 0.2f
#define PK_LOW  0x3FFFu
#define PK_HIGH 0xFFFFC000u
#define NGRP   (NN * NN / 256)     // 147456 groups of 256 cols
#define GPW    18                  // groups per wave: NGRP / 8192 waves
#define GEMMB  ((NN / 64) * NH)    // 288 gemm blocks
#define BITSB  2048                // 8192 scan waves
#define TOTB   (BITSB + GEMMB)     // 2336

typedef unsigned long long ull;

__device__ __forceinline__ float bf2f(ushort s) {
    return __uint_as_float((unsigned)s << 16);
}
__device__ __forceinline__ ushort f2bf(float f) {
    unsigned u = __float_as_uint(f);
    return (ushort)((u + 0x7FFFu + ((u >> 16) & 1u)) >> 16);   // RNE
}

// ============ K1: interleaved {adj->bits scan} + {layer-1 GEMM + Whb/es/ed} ==========
// LDS = 17.4KB (x-tile only; W streamed from L2) -> 8 blocks/CU, 32 waves: the scan
// keeps full occupancy (R12's 34.8KB halved it -> 0.6TB/s). GEMM = every 8th slot.
__global__ __launch_bounds__(256) void k_bits_gemm(const float* __restrict__ adj,
                                                   ull* __restrict__ bits,
                                                   const float* __restrict__ x,
                                                   const float* __restrict__ W,
                                                   const float* __restrict__ a_src,
                                                   const float* __restrict__ a_dst,
                                                   ushort* __restrict__ Whb,
                                                   float* __restrict__ es,
                                                   float* __restrict__ ed) {
    __shared__ float xs[64][68];   // 17408 B -- keep <= 20KB!
    int bid = blockIdx.x;
    int tid = threadIdx.x;
    int lane = tid & 63;
    int pg = bid >> 3;
    bool isGemm = ((bid & 7) == 7) && (pg < GEMMB);

    if (!isGemm) {
        // ---- scan role: 18 contiguous 1KB float4 loads/wave, zero serial deps ----
        int prior = pg < GEMMB ? pg : GEMMB;
        int bi = bid - prior;                    // 0..BITSB-1
        int gwid = bi * 4 + (tid >> 6);          // 0..8191
        const float* p = adj + (size_t)gwid * GPW * 256 + lane * 4;
        ull* bp = bits + (size_t)gwid * GPW * 4;
        for (int t = 0; t < 3; t++) {
            float4 v[6];
#pragma unroll
            for (int i = 0; i < 6; i++)
                v[i] = *reinterpret_cast<const float4*>(p + (t * 6 + i) * 256);
#pragma unroll
            for (int i = 0; i < 6; i++) {
                ull b0 = __ballot(v[i].x > 0.f);
                ull b1 = __ballot(v[i].y > 0.f);
                ull b2 = __ballot(v[i].z > 0.f);
                ull b3 = __ballot(v[i].w > 0.f);
                if (lane == 0) {
                    ulonglong2* q = reinterpret_cast<ulonglong2*>(bp + (size_t)(t * 6 + i) * 4);
                    ulonglong2 w0; w0.x = b0; w0.y = b1;
                    ulonglong2 w1; w1.x = b2; w1.y = b3;
                    q[0] = w0; q[1] = w1;
                }
            }
        }
        return;
    }

    // ---- GEMM role: Wh1[h][n0..n0+64][0..64], full K=512; W streamed from L2 ----
    int gb = pg;
    int h  = gb / (NN / 64);
    int n0 = (gb % (NN / 64)) * 64;
    int og4 = (tid & 15) * 4;
    int mg4 = (tid >> 4) * 4;

    float acc[4][4] = {{0.f}};
    const float* xbase0 = x + (size_t)n0 * FIN;
    const float* wbase0 = W + (size_t)h * FIN * HIDN;

    for (int t = 0; t < 8; t++) {
        int k0 = t * 64;
#pragma unroll
        for (int i = 0; i < 4; i++) {
            int l = tid + i * 256;
            int r = l >> 4;
            int c = (l & 15) * 4;
            *reinterpret_cast<float4*>(&xs[r][c]) =
                *reinterpret_cast<const float4*>(xbase0 + (size_t)r * FIN + k0 + c);
        }
        __syncthreads();

#pragma unroll 4
        for (int k = 0; k < 64; k += 4) {
            float4 xv[4], wv[4];
            xv[0] = *reinterpret_cast<const float4*>(&xs[mg4 + 0][k]);
            xv[1] = *reinterpret_cast<const float4*>(&xs[mg4 + 1][k]);
            xv[2] = *reinterpret_cast<const float4*>(&xs[mg4 + 2][k]);
            xv[3] = *reinterpret_cast<const float4*>(&xs[mg4 + 3][k]);
            wv[0] = *reinterpret_cast<const float4*>(wbase0 + (size_t)(k0 + k + 0) * HIDN + og4);
            wv[1] = *reinterpret_cast<const float4*>(wbase0 + (size_t)(k0 + k + 1) * HIDN + og4);
            wv[2] = *reinterpret_cast<const float4*>(wbase0 + (size_t)(k0 + k + 2) * HIDN + og4);
            wv[3] = *reinterpret_cast<const float4*>(wbase0 + (size_t)(k0 + k + 3) * HIDN + og4);
            const float* xf = reinterpret_cast<const float*>(xv);
            const float* wf = reinterpret_cast<const float*>(wv);
#pragma unroll
            for (int i = 0; i < 4; i++) {
#pragma unroll
                for (int kk = 0; kk < 4; kk++) {
                    float xval = xf[i * 4 + kk];
#pragma unroll
                    for (int j = 0; j < 4; j++)
                        acc[i][j] += xval * wf[kk * 4 + j];
                }
            }
        }
        __syncthreads();
    }

    // epilogue: bf16 store + es/ed (block owns the full 64-wide hidden dim)
    size_t rowbase = (size_t)h * NN + n0 + mg4;
#pragma unroll
    for (int i = 0; i < 4; i++) {
        ushort4 b;
        b.x = f2bf(acc[i][0]); b.y = f2bf(acc[i][1]);
        b.z = f2bf(acc[i][2]); b.w = f2bf(acc[i][3]);
        *reinterpret_cast<ushort4*>(Whb + (rowbase + i) * HIDN + og4) = b;
    }
    float as4[4], ad4[4];
#pragma unroll
    for (int j = 0; j < 4; j++) {
        as4[j] = a_src[h * HIDN + og4 + j];
        ad4[j] = a_dst[h * HIDN + og4 + j];
    }
    float se[4], de[4];
#pragma unroll
    for (int i = 0; i < 4; i++) {
        se[i] = acc[i][0] * as4[0] + acc[i][1] * as4[1] + acc[i][2] * as4[2] + acc[i][3] * as4[3];
        de[i] = acc[i][0] * ad4[0] + acc[i][1] * ad4[1] + acc[i][2] * ad4[2] + acc[i][3] * ad4[3];
    }
#pragma unroll
    for (int off = 1; off < 16; off <<= 1) {
#pragma unroll
        for (int i = 0; i < 4; i++) {
            se[i] += __shfl_xor(se[i], off);
            de[i] += __shfl_xor(de[i], off);
        }
    }
    if ((tid & 15) == 0) {
#pragma unroll
        for (int i = 0; i < 4; i++) {
            es[rowbase + i] = se[i];
            ed[rowbase + i] = de[i];
        }
    }
}

// ===== K2: bits-decode (wave 0) + layer-1 attention + head-mean + ReLU
//       + layer-2 GEMM + e2; persists nbr/deg for K3. block=192, grid=NN =====
__global__ __launch_bounds__(192) void k_attn1f(const ull* __restrict__ bits,
                                                int* __restrict__ nbr,
                                                int* __restrict__ deg,
                                                const ushort* __restrict__ Whb,
                                                const float* __restrict__ es,
                                                const float* __restrict__ ed,
                                                const float* __restrict__ W2,
                                                const float* __restrict__ a2s,
                                                const float* __restrict__ a2d,
                                                ushort* __restrict__ Wh2b,
                                                float* __restrict__ e2s,
                                                float* __restrict__ e2d) {
    __shared__ int nbrL[CAP];
    __shared__ int degS;
    __shared__ unsigned pks[NH][CAP];
    __shared__ float hsum[NH][HIDN];
    int n = blockIdx.x;
    int h = threadIdx.x >> 6;
    int lane = threadIdx.x & 63;

    if (h == 0) {
        // decode row n: word W, bit b -> col (W>>2)*256 + 4*b + (W&3)
        const ull* brow = bits + (size_t)n * 96;
        int W0 = lane, W1 = 64 + lane;
        ull m0 = brow[W0];
        ull m1 = (lane < 32) ? brow[W1] : 0ull;
        int c0 = __popcll(m0), c1 = __popcll(m1);
        int s0 = c0, s1 = c1;
#pragma unroll
        for (int off = 1; off < 64; off <<= 1) {
            int t0 = __shfl_up(s0, off);
            int t1 = __shfl_up(s1, off);
            if (lane >= off) { s0 += t0; s1 += t1; }
        }
        int total0 = __shfl(s0, 63);
        int total  = total0 + __shfl(s1, 63);
        int pre0 = s0 - c0;
        int pre1 = total0 + (s1 - c1);
        if (lane == 0) degS = total < CAP ? total : CAP;
        int g0 = (W0 >> 2) * 256 + (W0 & 3);
        int pos = pre0;
        while (m0) {
            int b = __builtin_ctzll(m0); m0 &= m0 - 1;
            if (pos < CAP) nbrL[pos] = g0 + 4 * b;
            pos++;
        }
        int g1 = (W1 >> 2) * 256 + (W1 & 3);
        pos = pre1;
        while (m1) {
            int b = __builtin_ctzll(m1); m1 &= m1 - 1;
            if (pos < CAP) nbrL[pos] = g1 + 4 * b;
            pos++;
        }
    }
    __syncthreads();
    int d = degS;
    if (threadIdx.x < CAP)
        nbr[(size_t)n * CAP + threadIdx.x] = ((int)threadIdx.x < d) ? nbrL[threadIdx.x] : 0;
    if (threadIdx.x == 0) deg[n] = d;

    float esv = es[h * NN + n];
    float psum = 0.f;
#pragma unroll
    for (int c = 0; c < NCHUNK; c++) {
        int k = c * 64 + lane;
        unsigned u = 0;
        if (k < d) {
            int mm = nbrL[k];
            float e = esv + ed[h * NN + mm];
            float s = e > 0.f ? e : LALPHA * e;
            float p = __expf(s);
            u = (__float_as_uint(p) & PK_HIGH) | (unsigned)mm;
            psum += __uint_as_float(u & PK_HIGH);
        }
        pks[h][k] = u;
    }
#pragma unroll
    for (int off = 32; off; off >>= 1) psum += __shfl_xor(psum, off);
    float inv = 1.f / psum;
    __syncthreads();

    const ushort* WhH = Whb + (size_t)h * NN * HIDN + lane;
    float a0 = 0.f, a1 = 0.f, a2 = 0.f, a3 = 0.f;
    int iters = (d + 3) >> 2;
    for (int g = 0; g < iters; g++) {
        uint4 uu = *reinterpret_cast<const uint4*>(&pks[h][g * 4]);
        a0 += __uint_as_float(uu.x & PK_HIGH) * bf2f(WhH[(size_t)(uu.x & PK_LOW) * HIDN]);
        a1 += __uint_as_float(uu.y & PK_HIGH) * bf2f(WhH[(size_t)(uu.y & PK_LOW) * HIDN]);
        a2 += __uint_as_float(uu.z & PK_HIGH) * bf2f(WhH[(size_t)(uu.z & PK_LOW) * HIDN]);
        a3 += __uint_as_float(uu.w & PK_HIGH) * bf2f(WhH[(size_t)(uu.w & PK_LOW) * HIDN]);
    }
    float hacc = ((a0 + a1) + (a2 + a3));
    hsum[h][lane] = hacc * inv;
    __syncthreads();

    float xv = (hsum[0][lane] + hsum[1][lane] + hsum[2][lane]) * (1.f / NH);
    xv = fmaxf(xv, 0.f);

    int c = lane < NC ? lane : NC - 1;
    float acc = 0.f;
#pragma unroll 8
    for (int o = 0; o < HIDN; o++) {
        float xb = __shfl(xv, o);
        float wv = W2[((size_t)h * HIDN + o) * NC + c];
        acc += xb * wv;
    }
    if (lane >= NC) acc = 0.f;

    float s2 = acc * (lane < NC ? a2s[h * NC + lane] : 0.f);
    float d2 = acc * (lane < NC ? a2d[h * NC + lane] : 0.f);
#pragma unroll
    for (int off = 32; off; off >>= 1) {
        s2 += __shfl_xor(s2, off);
        d2 += __shfl_xor(d2, off);
    }
    if (lane < NC) Wh2b[((size_t)h * NN + n) * NC + lane] = f2bf(acc);
    if (lane == 0) { e2s[h * NN + n] = s2; e2d[h * NN + n] = d2; }
}

// ---------------- K3: Layer-2 attention + head-mean + log_softmax ----------------
__global__ __launch_bounds__(192) void k_attn2(const int* __restrict__ nbr,
                                               const int* __restrict__ deg,
                                               const ushort* __restrict__ Wh2b,
                                               const float* __restrict__ es,
                                               const float* __restrict__ ed,
                                               float* __restrict__ out) {
    __shared__ unsigned pks[NH][CAP];
    __shared__ float hsum[NH][HIDN];
    int n = blockIdx.x;
    int h = threadIdx.x >> 6;
    int lane = threadIdx.x & 63;
    int d = deg[n];
    const int* nrow = nbr + (size_t)n * CAP;
    float esv = es[h * NN + n];

    float psum = 0.f;
#pragma unroll
    for (int c = 0; c < NCHUNK; c++) {
        int k = c * 64 + lane;
        unsigned u = 0;
        if (k < d) {
            int mm = nrow[k];
            float e = esv + ed[h * NN + mm];
            float s = e > 0.f ? e : LALPHA * e;
            float p = __expf(s);
            u = (__float_as_uint(p) & PK_HIGH) | (unsigned)mm;
            psum += __uint_as_float(u & PK_HIGH);
        }
        pks[h][k] = u;
    }
#pragma unroll
    for (int off = 32; off; off >>= 1) psum += __shfl_xor(psum, off);
    float inv = 1.f / psum;
    __syncthreads();

    const ushort* W2H = Wh2b + (size_t)h * NN * NC + (lane < NC ? lane : 0);
    float a0 = 0.f, a1 = 0.f, a2 = 0.f, a3 = 0.f;
    int iters = (d + 3) >> 2;
    for (int g = 0; g < iters; g++) {
        uint4 uu = *reinterpret_cast<const uint4*>(&pks[h][g * 4]);
        a0 += __uint_as_float(uu.x & PK_HIGH) * bf2f(W2H[(size_t)(uu.x & PK_LOW) * NC]);
        a1 += __uint_as_float(uu.y & PK_HIGH) * bf2f(W2H[(size_t)(uu.y & PK_LOW) * NC]);
        a2 += __uint_as_float(uu.z & PK_HIGH) * bf2f(W2H[(size_t)(uu.z & PK_LOW) * NC]);
        a3 += __uint_as_float(uu.w & PK_HIGH) * bf2f(W2H[(size_t)(uu.w & PK_LOW) * NC]);
    }
    float hacc = ((a0 + a1) + (a2 + a3));
    if (lane < NC) hsum[h][lane] = hacc * inv;
    __syncthreads();

    if (threadIdx.x < 64) {
        float a = (lane < NC)
            ? (hsum[0][lane] + hsum[1][lane] + hsum[2][lane]) * (1.f / NH)
            : -INFINITY;
        float mx = a;
#pragma unroll
        for (int off = 32; off; off >>= 1) mx = fmaxf(mx, __shfl_xor(mx, off));
        float ex = (lane < NC) ? __expf(a - mx) : 0.f;
        float se = ex;
#pragma unroll
        for (int off = 32; off; off >>= 1) se += __shfl_xor(se, off);
        if (lane < NC) out[(size_t)n * NC + lane] = a - mx - logf(se);
    }
}

extern "C" void kernel_launch(void* const* d_in, const int* in_sizes, int n_in,
                              void* d_out, int out_size, void* d_ws, size_t ws_size,
                              hipStream_t stream) {
    const float* feature = (const float*)d_in[0];
    const float* adj     = (const float*)d_in[1];
    const float* W1      = (const float*)d_in[2];
    const float* a1_src  = (const float*)d_in[3];
    const float* a1_dst  = (const float*)d_in[4];
    const float* W2      = (const float*)d_in[5];
    const float* a2_src  = (const float*)d_in[6];
    const float* a2_dst  = (const float*)d_in[7];
    float* out = (float*)d_out;

    char* ws = (char*)d_ws;
    size_t off = 0;
    ull*    bits = (ull*)(ws + off);   off += (size_t)NGRP * 4 * sizeof(ull);
    int*    nbr = (int*)(ws + off);    off += (size_t)NN * CAP * sizeof(int);
    int*    deg = (int*)(ws + off);    off += (size_t)NN * sizeof(int);
    ushort* Whb = (ushort*)(ws + off); off += (size_t)NH * NN * HIDN * sizeof(ushort);
    float*  e1s = (float*)(ws + off);  off += (size_t)NH * NN * sizeof(float);
    float*  e1d = (float*)(ws + off);  off += (size_t)NH * NN * sizeof(float);
    ushort* Wh2b= (ushort*)(ws + off); off += (size_t)NH * NN * NC * sizeof(ushort);
    float*  e2s = (float*)(ws + off);  off += (size_t)NH * NN * sizeof(float);
    float*  e2d = (float*)(ws + off);  off += (size_t)NH * NN * sizeof(float);

    k_bits_gemm<<<TOTB, 256, 0, stream>>>(adj, bits, feature, W1, a1_src, a1_dst,
                                          Whb, e1s, e1d);
    k_attn1f<<<NN, 192, 0, stream>>>(bits, nbr, deg, Whb, e1s, e1d, W2, a2_src, a2_dst,
                                     Wh2b, e2s, e2d);
    k_attn2<<<NN, 192, 0, stream>>>(nbr, deg, Wh2b, e2s, e2d, out);
}

// Round 14
// 94.443 us; speedup vs baseline: 2.2132x; 2.2132x over previous
//
#include <hip/hip_runtime.h>
#include <math.h>

#define NN   6144
#define FIN  512
#define HIDN 64
#define NC   40
#define NH   3
#define CAP  128           // max neighbors kept (deg ~61 +/- 8; 128 ~ 8.3 sigma)
#define NCHUNK (CAP / 64)
#define LALPHA 0.2f
#define KSPLIT 4
#define PK_LOW  0x3FFFu
#define PK_HIGH 0xFFFFC000u

typedef unsigned long long ull;

__device__ __forceinline__ float bf2f(ushort s) {
    return __uint_as_float((unsigned)s << 16);
}
__device__ __forceinline__ ushort f2bf(float f) {
    unsigned u = __float_as_uint(f);
    return (ushort)((u + 0x7FFFu + ((u >> 16) & 1u)) >> 16);   // RNE
}

// ---------------- Layer-1 GEMM, K-split: partial[z] = x[:,kz] * W1[h][kz,:] ----------
__global__ __launch_bounds__(256) void k_gemm1(const float* __restrict__ x,
                                               const float* __restrict__ W,
                                               float* __restrict__ Whp) {
    __shared__ float xs[64][68];   // [m][k]
    __shared__ float wsh[64][68];  // [k][o]
    int h  = blockIdx.y;
    int n0 = blockIdx.x * 64;
    int kz = blockIdx.z;
    int tid = threadIdx.x;
    int og4 = (tid & 15) * 4;
    int mg4 = (tid >> 4) * 4;

    float acc[4][4] = {{0.f}};
    const float* xbase0 = x + (size_t)n0 * FIN;
    const float* wbase0 = W + (size_t)h * FIN * HIDN;

    for (int t = 0; t < 2; t++) {
        int k0 = kz * 128 + t * 64;
#pragma unroll
        for (int i = 0; i < 4; i++) {
            int l = tid + i * 256;
            int r = l >> 4;
            int c = (l & 15) * 4;
            *reinterpret_cast<float4*>(&xs[r][c]) =
                *reinterpret_cast<const float4*>(xbase0 + (size_t)r * FIN + k0 + c);
            *reinterpret_cast<float4*>(&wsh[r][c]) =
                *reinterpret_cast<const float4*>(wbase0 + (size_t)(k0 + r) * HIDN + c);
        }
        __syncthreads();

#pragma unroll 8
        for (int k = 0; k < 64; k += 4) {
            float4 xv[4], wv[4];
            xv[0] = *reinterpret_cast<const float4*>(&xs[mg4 + 0][k]);
            xv[1] = *reinterpret_cast<const float4*>(&xs[mg4 + 1][k]);
            xv[2] = *reinterpret_cast<const float4*>(&xs[mg4 + 2][k]);
            xv[3] = *reinterpret_cast<const float4*>(&xs[mg4 + 3][k]);
            wv[0] = *reinterpret_cast<const float4*>(&wsh[k + 0][og4]);
            wv[1] = *reinterpret_cast<const float4*>(&wsh[k + 1][og4]);
            wv[2] = *reinterpret_cast<const float4*>(&wsh[k + 2][og4]);
            wv[3] = *reinterpret_cast<const float4*>(&wsh[k + 3][og4]);
            const float* xf = reinterpret_cast<const float*>(xv);
            const float* wf = reinterpret_cast<const float*>(wv);
#pragma unroll
            for (int i = 0; i < 4; i++) {
#pragma unroll
                for (int kk = 0; kk < 4; kk++) {
                    float xval = xf[i * 4 + kk];
#pragma unroll
                    for (int j = 0; j < 4; j++)
                        acc[i][j] += xval * wf[kk * 4 + j];
                }
            }
        }
        __syncthreads();
    }

    float* outp = Whp + (((size_t)kz * NH + h) * NN + n0 + mg4) * HIDN + og4;
#pragma unroll
    for (int i = 0; i < 4; i++) {
        float4 v = make_float4(acc[i][0], acc[i][1], acc[i][2], acc[i][3]);
        *reinterpret_cast<float4*>(outp + (size_t)i * HIDN) = v;
    }
}

// ---------------- sum K-split partials -> Wh1 (bf16), and compute es/ed (fp32) --------
__global__ __launch_bounds__(256) void k_sum_e1(const float* __restrict__ Whp,
                                                const float* __restrict__ a_src,
                                                const float* __restrict__ a_dst,
                                                ushort* __restrict__ Whb,
                                                float* __restrict__ es,
                                                float* __restrict__ ed) {
    int gw   = blockIdx.x * 4 + (threadIdx.x >> 6);
    int lane = threadIdx.x & 63;
    int h = gw / NN, n = gw % NN;
    size_t idx = ((size_t)h * NN + n) * HIDN + lane;
    size_t stride = (size_t)NH * NN * HIDN;
    float v = Whp[idx] + Whp[idx + stride] + Whp[idx + 2 * stride] + Whp[idx + 3 * stride];
    Whb[idx] = f2bf(v);
    float s = v * a_src[h * HIDN + lane];
    float d = v * a_dst[h * HIDN + lane];
#pragma unroll
    for (int off = 32; off; off >>= 1) {
        s += __shfl_xor(s, off);
        d += __shfl_xor(d, off);
    }
    if (lane == 0) { es[h * NN + n] = s; ed[h * NN + n] = d; }
}

// ---- Layer-1: in-block CSR build (adj row n) + attention + head-mean + ReLU
//      + layer-2 GEMM + e2. block = 192 (3 waves); grid = NN.
//      Scan phase: ALL 8 float4 loads issued before the ballot chain (8KB in
//      flight/wave); the compaction chain then runs on registers only. ----
__global__ __launch_bounds__(192) void k_attn1f(const float* __restrict__ adj,
                                                int* __restrict__ nbr,
                                                int* __restrict__ deg,
                                                const ushort* __restrict__ Whb,
                                                const float* __restrict__ es,
                                                const float* __restrict__ ed,
                                                const float* __restrict__ W2,
                                                const float* __restrict__ a2s,
                                                const float* __restrict__ a2d,
                                                ushort* __restrict__ Wh2b,
                                                float* __restrict__ e2s,
                                                float* __restrict__ e2d) {
    __shared__ int stage[NH][64];
    __shared__ int wtot[NH];
    __shared__ int nbrL[CAP];
    __shared__ unsigned pks[NH][CAP];
    __shared__ float hsum[NH][HIDN];

    int n = blockIdx.x;
    int h = threadIdx.x >> 6;       // wave id = head id = csr column-third
    int lane = threadIdx.x & 63;

    // ---- phase 0: build neighbor list for row n (each wave scans 2048 cols) ----
    {
        const float* base = adj + (size_t)n * NN + h * 2048;
        float4 v[8];
#pragma unroll
        for (int ch = 0; ch < 8; ch++)
            v[ch] = *reinterpret_cast<const float4*>(base + ch * 256 + lane * 4);
        ull below = (1ull << lane) - 1ull;
        int cnt = 0;
#pragma unroll
        for (int ch = 0; ch < 8; ch++) {
            bool h0 = v[ch].x > 0.f, h1 = v[ch].y > 0.f,
                 h2 = v[ch].z > 0.f, h3 = v[ch].w > 0.f;
            ull b0 = __ballot(h0), b1 = __ballot(h1), b2 = __ballot(h2), b3 = __ballot(h3);
            int p = cnt + __popcll(b0 & below) + __popcll(b1 & below)
                        + __popcll(b2 & below) + __popcll(b3 & below);
            int col = h * 2048 + ch * 256 + lane * 4;
            if (h0) { if (p < 64) stage[h][p] = col + 0; p++; }
            if (h1) { if (p < 64) stage[h][p] = col + 1; p++; }
            if (h2) { if (p < 64) stage[h][p] = col + 2; p++; }
            if (h3) { if (p < 64) stage[h][p] = col + 3; p++; }
            cnt += __popcll(b0) + __popcll(b1) + __popcll(b2) + __popcll(b3);
        }
        if (lane == 0) wtot[h] = cnt;
    }
    __syncthreads();
    int t0 = wtot[0], t1 = wtot[1], t2 = wtot[2];
    int pre = (h > 0 ? t0 : 0) + (h > 1 ? t1 : 0);
    int d = t0 + t1 + t2;
    if (d > CAP) d = CAP;
    {
        int myc = wtot[h] < 64 ? wtot[h] : 64;
        if (lane < myc && pre + lane < CAP) nbrL[pre + lane] = stage[h][lane];
    }
    __syncthreads();
    // persist for attn2
    if (threadIdx.x < CAP) nbr[(size_t)n * CAP + threadIdx.x] =
        ((int)threadIdx.x < d) ? nbrL[threadIdx.x] : 0;
    if (threadIdx.x == 0) deg[n] = d;

    // ---- phase 1: scores + softmax-denominator (per head-wave) ----
    float esv = es[h * NN + n];
    float psum = 0.f;
#pragma unroll
    for (int c = 0; c < NCHUNK; c++) {
        int k = c * 64 + lane;
        unsigned u = 0;
        if (k < d) {
            int mm = nbrL[k];
            float e = esv + ed[h * NN + mm];
            float s = e > 0.f ? e : LALPHA * e;
            float p = __expf(s);
            u = (__float_as_uint(p) & PK_HIGH) | (unsigned)mm;
            psum += __uint_as_float(u & PK_HIGH);
        }
        pks[h][k] = u;
    }
#pragma unroll
    for (int off = 32; off; off >>= 1) psum += __shfl_xor(psum, off);
    float inv = 1.f / psum;
    __syncthreads();

    // ---- phase 2: aggregate (4 neighbors/iter, bf16 payloads) ----
    const ushort* WhH = Whb + (size_t)h * NN * HIDN + lane;
    float a0 = 0.f, a1 = 0.f, a2 = 0.f, a3 = 0.f;
    int iters = (d + 3) >> 2;
    for (int g = 0; g < iters; g++) {
        uint4 uu = *reinterpret_cast<const uint4*>(&pks[h][g * 4]);
        a0 += __uint_as_float(uu.x & PK_HIGH) * bf2f(WhH[(size_t)(uu.x & PK_LOW) * HIDN]);
        a1 += __uint_as_float(uu.y & PK_HIGH) * bf2f(WhH[(size_t)(uu.y & PK_LOW) * HIDN]);
        a2 += __uint_as_float(uu.z & PK_HIGH) * bf2f(WhH[(size_t)(uu.z & PK_LOW) * HIDN]);
        a3 += __uint_as_float(uu.w & PK_HIGH) * bf2f(WhH[(size_t)(uu.w & PK_LOW) * HIDN]);
    }
    float hacc = ((a0 + a1) + (a2 + a3));
    hsum[h][lane] = hacc * inv;
    __syncthreads();

    // ---- phase 3: head-mean + ReLU + layer-2 linear + e2 (per head-wave) ----
    float xv = (hsum[0][lane] + hsum[1][lane] + hsum[2][lane]) * (1.f / NH);
    xv = fmaxf(xv, 0.f);

    int c = lane < NC ? lane : NC - 1;
    float acc = 0.f;
#pragma unroll 8
    for (int o = 0; o < HIDN; o++) {
        float xb = __shfl(xv, o);
        float wv = W2[((size_t)h * HIDN + o) * NC + c];
        acc += xb * wv;
    }
    if (lane >= NC) acc = 0.f;

    float s2 = acc * (lane < NC ? a2s[h * NC + lane] : 0.f);
    float d2 = acc * (lane < NC ? a2d[h * NC + lane] : 0.f);
#pragma unroll
    for (int off = 32; off; off >>= 1) {
        s2 += __shfl_xor(s2, off);
        d2 += __shfl_xor(d2, off);
    }
    if (lane < NC) Wh2b[((size_t)h * NN + n) * NC + lane] = f2bf(acc);
    if (lane == 0) { e2s[h * NN + n] = s2; e2d[h * NN + n] = d2; }
}

// ---------------- Layer-2 attention + head-mean + log_softmax ----------------
__global__ __launch_bounds__(192) void k_attn2(const int* __restrict__ nbr,
                                               const int* __restrict__ deg,
                                               const ushort* __restrict__ Wh2b,
                                               const float* __restrict__ es,
                                               const float* __restrict__ ed,
                                               float* __restrict__ out) {
    __shared__ unsigned pks[NH][CAP];
    __shared__ float hsum[NH][HIDN];
    int n = blockIdx.x;
    int h = threadIdx.x >> 6;
    int lane = threadIdx.x & 63;
    int d = deg[n];
    const int* nrow = nbr + (size_t)n * CAP;
    float esv = es[h * NN + n];

    float psum = 0.f;
#pragma unroll
    for (int c = 0; c < NCHUNK; c++) {
        int k = c * 64 + lane;
        unsigned u = 0;
        if (k < d) {
            int mm = nrow[k];
            float e = esv + ed[h * NN + mm];
            float s = e > 0.f ? e : LALPHA * e;
            float p = __expf(s);
            u = (__float_as_uint(p) & PK_HIGH) | (unsigned)mm;
            psum += __uint_as_float(u & PK_HIGH);
        }
        pks[h][k] = u;
    }
#pragma unroll
    for (int off = 32; off; off >>= 1) psum += __shfl_xor(psum, off);
    float inv = 1.f / psum;
    __syncthreads();

    const ushort* W2H = Wh2b + (size_t)h * NN * NC + (lane < NC ? lane : 0);
    float a0 = 0.f, a1 = 0.f, a2 = 0.f, a3 = 0.f;
    int iters = (d + 3) >> 2;
    for (int g = 0; g < iters; g++) {
        uint4 uu = *reinterpret_cast<const uint4*>(&pks[h][g * 4]);
        a0 += __uint_as_float(uu.x & PK_HIGH) * bf2f(W2H[(size_t)(uu.x & PK_LOW) * NC]);
        a1 += __uint_as_float(uu.y & PK_HIGH) * bf2f(W2H[(size_t)(uu.y & PK_LOW) * NC]);
        a2 += __uint_as_float(uu.z & PK_HIGH) * bf2f(W2H[(size_t)(uu.z & PK_LOW) * NC]);
        a3 += __uint_as_float(uu.w & PK_HIGH) * bf2f(W2H[(size_t)(uu.w & PK_LOW) * NC]);
    }
    float hacc = ((a0 + a1) + (a2 + a3));
    if (lane < NC) hsum[h][lane] = hacc * inv;
    __syncthreads();

    if (threadIdx.x < 64) {
        float a = (lane < NC)
            ? (hsum[0][lane] + hsum[1][lane] + hsum[2][lane]) * (1.f / NH)
            : -INFINITY;
        float mx = a;
#pragma unroll
        for (int off = 32; off; off >>= 1) mx = fmaxf(mx, __shfl_xor(mx, off));
        float ex = (lane < NC) ? __expf(a - mx) : 0.f;
        float se = ex;
#pragma unroll
        for (int off = 32; off; off >>= 1) se += __shfl_xor(se, off);
        if (lane < NC) out[(size_t)n * NC + lane] = a - mx - logf(se);
    }
}

extern "C" void kernel_launch(void* const* d_in, const int* in_sizes, int n_in,
                              void* d_out, int out_size, void* d_ws, size_t ws_size,
                              hipStream_t stream) {
    const float* feature = (const float*)d_in[0];
    const float* adj     = (const float*)d_in[1];
    const float* W1      = (const float*)d_in[2];
    const float* a1_src  = (const float*)d_in[3];
    const float* a1_dst  = (const float*)d_in[4];
    const float* W2      = (const float*)d_in[5];
    const float* a2_src  = (const float*)d_in[6];
    const float* a2_dst  = (const float*)d_in[7];
    float* out = (float*)d_out;

    char* ws = (char*)d_ws;
    size_t off = 0;
    int*    nbr = (int*)(ws + off);    off += (size_t)NN * CAP * sizeof(int);
    int*    deg = (int*)(ws + off);    off += (size_t)NN * sizeof(int);
    float*  Whp = (float*)(ws + off);  off += (size_t)KSPLIT * NH * NN * HIDN * sizeof(float);
    ushort* Whb = (ushort*)(ws + off); off += (size_t)NH * NN * HIDN * sizeof(ushort);
    float*  e1s = (float*)(ws + off);  off += (size_t)NH * NN * sizeof(float);
    float*  e1d = (float*)(ws + off);  off += (size_t)NH * NN * sizeof(float);
    ushort* Wh2b= (ushort*)(ws + off); off += (size_t)NH * NN * NC * sizeof(ushort);
    float*  e2s = (float*)(ws + off);  off += (size_t)NH * NN * sizeof(float);
    float*  e2d = (float*)(ws + off);  off += (size_t)NH * NN * sizeof(float);

    k_gemm1<<<dim3(NN / 64, NH, KSPLIT), 256, 0, stream>>>(feature, W1, Whp);
    k_sum_e1<<<(NH * NN) / 4, 256, 0, stream>>>(Whp, a1_src, a1_dst, Whb, e1s, e1d);
    k_attn1f<<<NN, 192, 0, stream>>>(adj, nbr, deg, Whb, e1s, e1d, W2, a2_src, a2_dst,
                                     Wh2b, e2s, e2d);
    k_attn2<<<NN, 192, 0, stream>>>(nbr, deg, Wh2b, e2s, e2d, out);
}